// Round 5
// baseline (73.010 us; speedup 1.0000x reference)
//
#include <hip/hip_runtime.h>
#include <hip/hip_fp16.h>
#include <stdint.h>

#define H 1024
#define BATCH 2048
#define KDIM 2048   // input + hidden concatenated
#define NDIM 4096   // 4 gates
#define EPS 1e-5f

#define BM 128
#define BN 128
#define BK 32

typedef __attribute__((ext_vector_type(8))) short bf16x8;
typedef __attribute__((ext_vector_type(4))) float f32x4;

#define FENCE asm volatile("" ::: "memory")

__device__ __forceinline__ unsigned short f2bf(float f) {
  uint32_t u = __float_as_uint(f);
  u += 0x7FFFu + ((u >> 16) & 1u);
  return (unsigned short)(u >> 16);
}

__device__ __forceinline__ float fast_sig(float x) {
  x = fminf(30.f, fmaxf(-30.f, x));
  float e = __expf(x);
  return e / (e + 1.f);
}

__device__ __forceinline__ float fast_tanh(float x) {
  x = fminf(15.f, fmaxf(-15.f, x));
  float e = __expf(2.f * x);
  return (e - 1.f) / (e + 1.f);
}

// ---------------- pack: f32 -> bf16, concat along K ----------------
__global__ __launch_bounds__(256) void pack_kernel(
    const float* __restrict__ x, const float* __restrict__ h,
    const float* __restrict__ Wih, const float* __restrict__ Whh,
    unsigned short* __restrict__ A, unsigned short* __restrict__ B) {
  int u = blockIdx.x * 256 + threadIdx.x;
  const int unitsA = BATCH * KDIM / 4;
  const float* src;
  unsigned short* dst;
  if (u < unitsA) {
    int m = u >> 9;
    int kv = (u & 511) << 2;
    src = (kv < H) ? (x + (size_t)m * H + kv) : (h + (size_t)m * H + (kv - H));
    dst = A + (size_t)m * KDIM + kv;
  } else {
    int v = u - unitsA;
    int m = v >> 9;
    int kv = (v & 511) << 2;
    src = (kv < H) ? (Wih + (size_t)m * H + kv) : (Whh + (size_t)m * H + (kv - H));
    dst = B + (size_t)m * KDIM + kv;
  }
  float4 f = *(const float4*)src;
  ushort4 o;
  o.x = f2bf(f.x);
  o.y = f2bf(f.y);
  o.z = f2bf(f.z);
  o.w = f2bf(f.w);
  *(ushort4*)dst = o;
}

// ---------------- GEMM: 128x128, BK=32 dbuf, counted vmcnt, 4 blocks/CU -----
__device__ __forceinline__ void load_lds16(const void* g, void* l) {
  __builtin_amdgcn_global_load_lds(
      (const __attribute__((address_space(1))) void*)g,
      (__attribute__((address_space(3))) void*)l, 16, 0, 0);
}

// swizzle: physical chunk = logical ^ s(row); s spreads 16 rows over 8
// (chunk,parity) bank groups -> 2-way aliasing = free (m136)
__device__ __forceinline__ int swz(int r) { return ((r & 3) ^ ((r >> 2) & 1)); }

__global__ __launch_bounds__(256, 4) void gemm_kernel(
    const unsigned short* __restrict__ A,  // 2048 x 2048 bf16
    const unsigned short* __restrict__ B,  // 4096 x 2048 bf16 (B^T layout)
    __half* __restrict__ P0, __half* __restrict__ P1) {
  __shared__ unsigned short sA[2][BM * BK];  // 2 x 8 KB
  __shared__ unsigned short sB[2][BN * BK];  // 2 x 8 KB

  const int tid = threadIdx.x;
  const int wave = tid >> 6;
  const int lane = tid & 63;
  const int m0 = blockIdx.y * BM;
  const int n0 = blockIdx.x * BN;
  const int kbase = blockIdx.z * (KDIM / 2);
  __half* __restrict__ P = blockIdx.z ? P1 : P0;
  const int wr = (wave >> 1) * 64;
  const int wc = (wave & 1) * 64;

  const int frow = lane & 15;
  const int kc = lane >> 4;       // logical 16B k-chunk 0..3
  const int sr = tid >> 2;        // staging row 0..63
  const int sc = tid & 3;         // staging (physical) chunk

  f32x4 acc[4][4] = {};

  const int NT = (KDIM / 2) / BK;  // 32

  auto stage = [&](int t, int buf) {
    const int k0 = kbase + t * BK;
#pragma unroll
    for (int q = 0; q < 2; ++q) {
      const int row = q * 64 + sr;
      const int gchunk = (sc ^ swz(row)) << 3;  // pre-swizzled global source
      load_lds16(A + (size_t)(m0 + row) * KDIM + k0 + gchunk,
                 (char*)sA[buf] + q * 4096 + wave * 1024);
      load_lds16(B + (size_t)(n0 + row) * KDIM + k0 + gchunk,
                 (char*)sB[buf] + q * 4096 + wave * 1024);
    }
  };

  stage(0, 0);

  for (int t = 0; t < NT; ++t) {
    const int cur = t & 1;
    if (t + 1 < NT) {
      stage(t + 1, cur ^ 1);  // buffer freed by end-barrier of t-1
      asm volatile("s_waitcnt vmcnt(4)" ::: "memory");  // own stage(t) landed
    } else {
      asm volatile("s_waitcnt vmcnt(0)" ::: "memory");
    }
    __builtin_amdgcn_s_barrier();  // now ALL waves' stage(t) portions landed
    FENCE;

    bf16x8 a[4], b[4];
#pragma unroll
    for (int i = 0; i < 4; ++i) {
      const int ra = wr + i * 16 + frow;
      const int rb = wc + i * 16 + frow;
      a[i] = *(const bf16x8*)((const char*)sA[cur] + ra * 64 + ((kc ^ swz(ra)) << 4));
      b[i] = *(const bf16x8*)((const char*)sB[cur] + rb * 64 + ((kc ^ swz(rb)) << 4));
    }
#pragma unroll
    for (int i = 0; i < 4; ++i)
#pragma unroll
      for (int j = 0; j < 4; ++j)
        acc[i][j] =
            __builtin_amdgcn_mfma_f32_16x16x32_bf16(a[i], b[j], acc[i][j], 0, 0, 0);

    FENCE;
    __builtin_amdgcn_s_barrier();  // all waves done reading buf[cur]
  }

  const int crow = (lane >> 4) << 2;
  const int ccol = lane & 15;
#pragma unroll
  for (int i = 0; i < 4; ++i)
#pragma unroll
    for (int j = 0; j < 4; ++j) {
      __half* cp = P + (size_t)(m0 + wr + i * 16 + crow) * NDIM + (n0 + wc + j * 16 + ccol);
#pragma unroll
      for (int r = 0; r < 4; ++r) cp[(size_t)r * NDIM] = __float2half(acc[i][j][r]);
    }
}

// ---------------- epilogue: sum partials + gates + c update + LN + h --------
__global__ __launch_bounds__(256) void epilogue_kernel(
    const __half* __restrict__ P0, const __half* __restrict__ P1,
    const float* __restrict__ c_in,
    const float* __restrict__ b_ih, const float* __restrict__ b_hh,
    const float* __restrict__ ln_w, const float* __restrict__ ln_b,
    float* __restrict__ h_out, float* __restrict__ c_out) {
  const int m = blockIdx.x;
  const int t = threadIdx.x;
  const int j = t << 2;
  const __half* r0 = P0 + (size_t)m * NDIM;
  const __half* r1 = P1 + (size_t)m * NDIM;

  float pre[4][4];
#pragma unroll
  for (int g = 0; g < 4; ++g) {
    ushort4 u0 = *(const ushort4*)(r0 + g * H + j);
    ushort4 u1 = *(const ushort4*)(r1 + g * H + j);
    float4 bi = *(const float4*)(b_ih + g * H + j);
    float4 bh = *(const float4*)(b_hh + g * H + j);
    pre[g][0] = __half2float(*(__half*)&u0.x) + __half2float(*(__half*)&u1.x) + bi.x + bh.x;
    pre[g][1] = __half2float(*(__half*)&u0.y) + __half2float(*(__half*)&u1.y) + bi.y + bh.y;
    pre[g][2] = __half2float(*(__half*)&u0.z) + __half2float(*(__half*)&u1.z) + bi.z + bh.z;
    pre[g][3] = __half2float(*(__half*)&u0.w) + __half2float(*(__half*)&u1.w) + bi.w + bh.w;
  }
  float4 ci = *(const float4*)(c_in + (size_t)m * H + j);

  float cr[4], vo[4];
  float s = 0.f, q = 0.f;
#pragma unroll
  for (int r = 0; r < 4; ++r) {
    float iv = fast_sig(pre[0][r]);
    float fv = fast_sig(pre[1][r]);
    float ov = fast_sig(pre[2][r]);
    float gv = fast_tanh(pre[3][r]);
    float cv = ((const float*)&ci)[r] * fv + iv * gv;
    cr[r] = cv;
    vo[r] = ov;
    s += cv;
    q += cv * cv;
  }

#pragma unroll
  for (int off = 32; off > 0; off >>= 1) {
    s += __shfl_xor(s, off);
    q += __shfl_xor(q, off);
  }
  __shared__ float red[8];
  const int wv = t >> 6, ln = t & 63;
  if (ln == 0) {
    red[wv] = s;
    red[wv + 4] = q;
  }
  __syncthreads();
  s = red[0] + red[1] + red[2] + red[3];
  q = red[4] + red[5] + red[6] + red[7];
  const float mu = s * (1.f / H);
  const float var = q * (1.f / H) - mu * mu;
  const float rstd = rsqrtf(var + EPS);

  float4 lw = *(const float4*)(ln_w + j);
  float4 lb = *(const float4*)(ln_b + j);
  float4 hov, cov;
#pragma unroll
  for (int r = 0; r < 4; ++r) {
    float cn = (cr[r] - mu) * rstd * ((const float*)&lw)[r] + ((const float*)&lb)[r];
    ((float*)&cov)[r] = cn;
    ((float*)&hov)[r] = vo[r] * fast_tanh(cn);
  }
  *(float4*)(h_out + (size_t)m * H + j) = hov;
  *(float4*)(c_out + (size_t)m * H + j) = cov;
}

extern "C" void kernel_launch(void* const* d_in, const int* in_sizes, int n_in,
                              void* d_out, int out_size, void* d_ws, size_t ws_size,
                              hipStream_t stream) {
  const float* x = (const float*)d_in[0];
  const float* h = (const float*)d_in[1];
  const float* c = (const float*)d_in[2];
  const float* Wih = (const float*)d_in[3];
  const float* b_ih = (const float*)d_in[4];
  const float* Whh = (const float*)d_in[5];
  const float* b_hh = (const float*)d_in[6];
  const float* ln_w = (const float*)d_in[7];
  const float* ln_b = (const float*)d_in[8];

  unsigned short* A = (unsigned short*)d_ws;                                      // 8 MB
  unsigned short* B = (unsigned short*)((char*)d_ws + (size_t)BATCH * KDIM * 2);  // 16 MB
  char* pbase = (char*)d_ws + (size_t)BATCH * KDIM * 2 + (size_t)NDIM * KDIM * 2;
  __half* P0 = (__half*)pbase;                               // 16 MB
  __half* P1 = (__half*)(pbase + (size_t)BATCH * NDIM * 2);  // 16 MB

  float* h_out = (float*)d_out;
  float* c_out = (float*)d_out + (size_t)BATCH * H;

  pack_kernel<<<12288, 256, 0, stream>>>(x, h, Wih, Whh, A, B);
  dim3 g(NDIM / BN, BATCH / BM, 2);
  gemm_kernel<<<g, 256, 0, stream>>>(A, B, P0, P1);
  epilogue_kernel<<<BATCH, 256, 0, stream>>>(P0, P1, c, b_ih, b_hh, ln_w, ln_b, h_out, c_out);
}

// Round 6
// 65.571 us; speedup vs baseline: 1.1134x; 1.1134x over previous
//
#include <hip/hip_runtime.h>
#include <hip/hip_fp16.h>
#include <stdint.h>

#define H 1024
#define BATCH 2048
#define KDIM 2048   // input + hidden concatenated
#define NDIM 4096   // 4 gates
#define EPS 1e-5f

#define BM 256
#define BN 256
#define BK 64
#define NK 16  // K-tiles per split-K half (1024/64)
#define NI 8   // iterations (2 tiles each)

typedef __attribute__((ext_vector_type(8))) short bf16x8;
typedef __attribute__((ext_vector_type(4))) float f32x4;

__device__ __forceinline__ unsigned short f2bf(float f) {
  uint32_t u = __float_as_uint(f);
  u += 0x7FFFu + ((u >> 16) & 1u);
  return (unsigned short)(u >> 16);
}

__device__ __forceinline__ float fast_sig(float x) {
  x = fminf(30.f, fmaxf(-30.f, x));
  float e = __expf(x);
  return e / (e + 1.f);
}

__device__ __forceinline__ float fast_tanh(float x) {
  x = fminf(15.f, fmaxf(-15.f, x));
  float e = __expf(2.f * x);
  return (e - 1.f) / (e + 1.f);
}

// ---------------- pack: f32 -> bf16, concat along K ----------------
__global__ __launch_bounds__(256) void pack_kernel(
    const float* __restrict__ x, const float* __restrict__ h,
    const float* __restrict__ Wih, const float* __restrict__ Whh,
    unsigned short* __restrict__ A, unsigned short* __restrict__ B) {
  int u = blockIdx.x * 256 + threadIdx.x;
  const int unitsA = BATCH * KDIM / 4;
  const float* src;
  unsigned short* dst;
  if (u < unitsA) {
    int m = u >> 9;
    int kv = (u & 511) << 2;
    src = (kv < H) ? (x + (size_t)m * H + kv) : (h + (size_t)m * H + (kv - H));
    dst = A + (size_t)m * KDIM + kv;
  } else {
    int v = u - unitsA;
    int m = v >> 9;
    int kv = (v & 511) << 2;
    src = (kv < H) ? (Wih + (size_t)m * H + kv) : (Whh + (size_t)m * H + (kv - H));
    dst = B + (size_t)m * KDIM + kv;
  }
  float4 f = *(const float4*)src;
  ushort4 o;
  o.x = f2bf(f.x);
  o.y = f2bf(f.y);
  o.z = f2bf(f.z);
  o.w = f2bf(f.w);
  *(ushort4*)dst = o;
}

// ---------------- GEMM: 256x256, 8-phase counted-vmcnt pipeline -------------
__device__ __forceinline__ void load_lds16(const void* g, void* l) {
  __builtin_amdgcn_global_load_lds(
      (const __attribute__((address_space(1))) void*)g,
      (__attribute__((address_space(3))) void*)l, 16, 0, 0);
}

// LDS map (bytes): buf b in {0,1}: A k-half h at b*65536 + h*16384,
//                  B k-half h at b*65536 + 32768 + h*16384.
// Each half: 256 rows x 32 k (64B rows). Swizzle: phys_chunk = c ^ ((row>>1)&3).

__global__ __launch_bounds__(512, 2) void gemm_kernel(
    const unsigned short* __restrict__ A,  // 2048 x 2048 bf16
    const unsigned short* __restrict__ B,  // 4096 x 2048 bf16 (B^T layout)
    __half* __restrict__ P0, __half* __restrict__ P1) {
  extern __shared__ char lds[];  // 131072 bytes

  const int tid = threadIdx.x;
  const int wave = tid >> 6;
  const int lane = tid & 63;
  const int m0 = blockIdx.y * BM;
  const int n0 = blockIdx.x * BN;
  const int kz = blockIdx.z * (KDIM / 2);
  __half* __restrict__ P = blockIdx.z ? P1 : P0;
  const int wm = wave >> 2;  // 0..1
  const int wn = wave & 3;   // 0..3
  const int frow = lane & 15;
  const int fhi = lane >> 4;

  // read-side swizzled chunk offset (bytes), constant per lane
  const int physc = ((fhi ^ ((frow >> 1) & 3)) << 4);
  const int aRowBase = (wm * 128 + frow) * 64 + physc;
  const int bRowBase = 32768 + (wn * 64 + frow) * 64 + physc;

  // stage-side: row = r*128 + wave*16 + (lane>>2); src chunk pre-XORed
  const int srowA = wave * 16 + (lane >> 2);
  const int schoff = (((lane & 3) ^ ((lane >> 3) & 3)) << 3);  // elements
  const unsigned short* Asrc = A + (size_t)(m0 + srowA) * KDIM + kz + schoff;
  const unsigned short* Bsrc = B + (size_t)(n0 + srowA) * KDIM + kz + schoff;
  char* dstb = lds + wave * 1024;  // + b*65536 (+32768 B) + h*16384 (+8192 r=1)

  f32x4 acc[8][4] = {};
  bf16x8 bf[4];

#define STAGE_A(T, hh, b)                                                     \
  {                                                                           \
    const unsigned short* s = Asrc + ((((T) & 15) << 6) + (hh) * 32);         \
    char* d = dstb + (b) * 65536 + (hh) * 16384;                              \
    load_lds16(s, d);                                                         \
    load_lds16(s + (size_t)128 * KDIM, d + 8192);                             \
  }
#define STAGE_B(T, hh, b)                                                     \
  {                                                                           \
    const unsigned short* s = Bsrc + ((((T) & 15) << 6) + (hh) * 32);         \
    char* d = dstb + (b) * 65536 + 32768 + (hh) * 16384;                      \
    load_lds16(s, d);                                                         \
    load_lds16(s + (size_t)128 * KDIM, d + 8192);                             \
  }

#define PHASE(b, ks, mh, LDB, STAGE_STMT, VM)                                  \
  {                                                                            \
    bf16x8 af[4];                                                              \
    _Pragma("unroll") for (int q = 0; q < 4; ++q) af[q] =                      \
        *(const bf16x8*)(lds + (b) * 65536 + (ks) * 16384 + aRowBase +         \
                         ((mh) * 4 + q) * 1024);                               \
    if (LDB) {                                                                 \
      _Pragma("unroll") for (int n = 0; n < 4; ++n) bf[n] =                    \
          *(const bf16x8*)(lds + (b) * 65536 + (ks) * 16384 + bRowBase +       \
                           n * 1024);                                          \
    }                                                                          \
    STAGE_STMT;                                                                \
    asm volatile("s_barrier" ::: "memory");                                    \
    __builtin_amdgcn_s_setprio(1);                                             \
    _Pragma("unroll") for (int q = 0; q < 4; ++q)                              \
        _Pragma("unroll") for (int n = 0; n < 4; ++n) acc[(mh)*4 + q][n] =     \
            __builtin_amdgcn_mfma_f32_16x16x32_bf16(af[q], bf[n],              \
                                                    acc[(mh)*4 + q][n], 0, 0,  \
                                                    0);                        \
    __builtin_amdgcn_s_setprio(0);                                             \
    if (VM) asm volatile("s_waitcnt vmcnt(6)" ::: "memory");                   \
    asm volatile("s_barrier" ::: "memory");                                    \
  }

  // prologue: T0.A0, T0.B0, T0.A1, T0.B1, T1.A0  (deadline order)
  STAGE_A(0, 0, 0);
  STAGE_B(0, 0, 0);
  STAGE_A(0, 1, 0);
  STAGE_B(0, 1, 0);
  STAGE_A(1, 0, 1);
  asm volatile("s_waitcnt vmcnt(6)" ::: "memory");  // T0.A0,B0 landed
  asm volatile("s_barrier" ::: "memory");

  for (int i = 0; i < NI; ++i) {
    const int t2 = 2 * i;
    PHASE(0, 0, 0, true,  STAGE_B(t2 + 1, 0, 1), false);  // ph1
    PHASE(0, 0, 1, false, STAGE_A(t2 + 1, 1, 1), true);   // ph2
    PHASE(0, 1, 0, true,  STAGE_B(t2 + 1, 1, 1), false);  // ph3
    PHASE(0, 1, 1, false, STAGE_A(t2 + 2, 0, 0), true);   // ph4
    PHASE(1, 0, 0, true,  STAGE_B(t2 + 2, 0, 0), false);  // ph5
    PHASE(1, 0, 1, false, STAGE_A(t2 + 2, 1, 0), true);   // ph6
    PHASE(1, 1, 0, true,  STAGE_B(t2 + 2, 1, 0), false);  // ph7
    PHASE(1, 1, 1, false, STAGE_A(t2 + 3, 0, 1), true);   // ph8
  }

  // store fp16 partials: row = m-side, col = n-side (verified R1 layout)
#pragma unroll
  for (int mi = 0; mi < 8; ++mi)
#pragma unroll
    for (int ni = 0; ni < 4; ++ni) {
      __half* cp = P + (size_t)(m0 + wm * 128 + mi * 16 + fhi * 4) * NDIM +
                   (n0 + wn * 64 + ni * 16 + frow);
#pragma unroll
      for (int r = 0; r < 4; ++r) cp[(size_t)r * NDIM] = __float2half(acc[mi][ni][r]);
    }
#undef STAGE_A
#undef STAGE_B
#undef PHASE
}

// ---------------- epilogue: sum partials + gates + c update + LN + h --------
__global__ __launch_bounds__(256) void epilogue_kernel(
    const __half* __restrict__ P0, const __half* __restrict__ P1,
    const float* __restrict__ c_in,
    const float* __restrict__ b_ih, const float* __restrict__ b_hh,
    const float* __restrict__ ln_w, const float* __restrict__ ln_b,
    float* __restrict__ h_out, float* __restrict__ c_out) {
  const int m = blockIdx.x;
  const int t = threadIdx.x;
  const int j = t << 2;
  const __half* r0 = P0 + (size_t)m * NDIM;
  const __half* r1 = P1 + (size_t)m * NDIM;

  float pre[4][4];
#pragma unroll
  for (int g = 0; g < 4; ++g) {
    ushort4 u0 = *(const ushort4*)(r0 + g * H + j);
    ushort4 u1 = *(const ushort4*)(r1 + g * H + j);
    float4 bi = *(const float4*)(b_ih + g * H + j);
    float4 bh = *(const float4*)(b_hh + g * H + j);
    pre[g][0] = __half2float(*(__half*)&u0.x) + __half2float(*(__half*)&u1.x) + bi.x + bh.x;
    pre[g][1] = __half2float(*(__half*)&u0.y) + __half2float(*(__half*)&u1.y) + bi.y + bh.y;
    pre[g][2] = __half2float(*(__half*)&u0.z) + __half2float(*(__half*)&u1.z) + bi.z + bh.z;
    pre[g][3] = __half2float(*(__half*)&u0.w) + __half2float(*(__half*)&u1.w) + bi.w + bh.w;
  }
  float4 ci = *(const float4*)(c_in + (size_t)m * H + j);

  float cr[4], vo[4];
  float s = 0.f, q = 0.f;
#pragma unroll
  for (int r = 0; r < 4; ++r) {
    float iv = fast_sig(pre[0][r]);
    float fv = fast_sig(pre[1][r]);
    float ov = fast_sig(pre[2][r]);
    float gv = fast_tanh(pre[3][r]);
    float cv = ((const float*)&ci)[r] * fv + iv * gv;
    cr[r] = cv;
    vo[r] = ov;
    s += cv;
    q += cv * cv;
  }

#pragma unroll
  for (int off = 32; off > 0; off >>= 1) {
    s += __shfl_xor(s, off);
    q += __shfl_xor(q, off);
  }
  __shared__ float red[8];
  const int wv = t >> 6, ln = t & 63;
  if (ln == 0) {
    red[wv] = s;
    red[wv + 4] = q;
  }
  __syncthreads();
  s = red[0] + red[1] + red[2] + red[3];
  q = red[4] + red[5] + red[6] + red[7];
  const float mu = s * (1.f / H);
  const float var = q * (1.f / H) - mu * mu;
  const float rstd = rsqrtf(var + EPS);

  float4 lw = *(const float4*)(ln_w + j);
  float4 lb = *(const float4*)(ln_b + j);
  float4 hov, cov;
#pragma unroll
  for (int r = 0; r < 4; ++r) {
    float cn = (cr[r] - mu) * rstd * ((const float*)&lw)[r] + ((const float*)&lb)[r];
    ((float*)&cov)[r] = cn;
    ((float*)&hov)[r] = vo[r] * fast_tanh(cn);
  }
  *(float4*)(h_out + (size_t)m * H + j) = hov;
  *(float4*)(c_out + (size_t)m * H + j) = cov;
}

extern "C" void kernel_launch(void* const* d_in, const int* in_sizes, int n_in,
                              void* d_out, int out_size, void* d_ws, size_t ws_size,
                              hipStream_t stream) {
  const float* x = (const float*)d_in[0];
  const float* h = (const float*)d_in[1];
  const float* c = (const float*)d_in[2];
  const float* Wih = (const float*)d_in[3];
  const float* b_ih = (const float*)d_in[4];
  const float* Whh = (const float*)d_in[5];
  const float* b_hh = (const float*)d_in[6];
  const float* ln_w = (const float*)d_in[7];
  const float* ln_b = (const float*)d_in[8];

  unsigned short* A = (unsigned short*)d_ws;                                      // 8 MB
  unsigned short* B = (unsigned short*)((char*)d_ws + (size_t)BATCH * KDIM * 2);  // 16 MB
  char* pbase = (char*)d_ws + (size_t)BATCH * KDIM * 2 + (size_t)NDIM * KDIM * 2;
  __half* P0 = (__half*)pbase;                               // 16 MB
  __half* P1 = (__half*)(pbase + (size_t)BATCH * NDIM * 2);  // 16 MB

  float* h_out = (float*)d_out;
  float* c_out = (float*)d_out + (size_t)BATCH * H;

  (void)hipFuncSetAttribute((const void*)gemm_kernel,
                            hipFuncAttributeMaxDynamicSharedMemorySize, 131072);

  pack_kernel<<<12288, 256, 0, stream>>>(x, h, Wih, Whh, A, B);
  dim3 g(NDIM / BN, BATCH / BM, 2);
  gemm_kernel<<<g, 512, 131072, stream>>>(A, B, P0, P1);
  epilogue_kernel<<<BATCH, 256, 0, stream>>>(P0, P1, c, b_ih, b_hh, ln_w, ln_b, h_out, c_out);
}